// Round 5
// baseline (1203.535 us; speedup 1.0000x reference)
//
#include <hip/hip_runtime.h>
#include <hip/hip_fp16.h>

#define N_NODES   100000
#define N_EDGES   3200000
#define N_FEAT    128
#define HIDDEN    16
#define N_CLASSES 10
#define N_GRAPHS  512
#define NPB       128                      // nodes per bucket
#define NBUCKET   782                      // ceil(N_NODES / NPB)
#define SLACK     4608                     // mean 4092, sigma 64 -> +8 sigma
#define EPT       16                       // edges per thread in partition

// ---------------- bucket partition with slack regions (no count/scan prepass) ----------------

__global__ void cursor_init_kernel(int* __restrict__ cur) {
    int i = blockIdx.x * 256 + threadIdx.x;
    if (i < NBUCKET) cur[i] = i * SLACK;
}

// scatter packed (src | (dst&127)<<17) into per-bucket slack regions
__global__ void partition_kernel(const int* __restrict__ src, const int* __restrict__ dst,
                                 int* __restrict__ cur, unsigned* __restrict__ part) {
    __shared__ int cnt[NBUCKET];
    __shared__ int base[NBUCKET];
    for (int i = threadIdx.x; i < NBUCKET; i += 256) cnt[i] = 0;
    __syncthreads();
    int blockStart = blockIdx.x * (256 * EPT);
    unsigned rec[EPT];
    int lr[EPT];
    int bkey[EPT];
#pragma unroll
    for (int i = 0; i < EPT; ++i) {
        int e = blockStart + i * 256 + threadIdx.x;
        if (e < N_EDGES) {
            int d = dst[e];
            int b = d >> 7;
            bkey[i] = b;
            lr[i]   = atomicAdd(&cnt[b], 1);
            rec[i]  = (unsigned)src[e] | ((unsigned)(d & 127) << 17);
        } else {
            lr[i] = -1;
        }
    }
    __syncthreads();
    for (int i = threadIdx.x; i < NBUCKET; i += 256) {
        int c = cnt[i];
        base[i] = c ? atomicAdd(&cur[i], c) : 0;
    }
    __syncthreads();
#pragma unroll
    for (int i = 0; i < EPT; ++i)
        if (lr[i] >= 0) part[base[bkey[i]] + lr[i]] = rec[i];
}

// per-bucket degree count -> dinv (replaces CSR build)
__global__ void deg_dinv_kernel(const unsigned* __restrict__ part, const int* __restrict__ cur,
                                float* __restrict__ dinv) {
    __shared__ int ncnt[NPB];
    int b   = blockIdx.x;
    int tid = threadIdx.x;
    if (tid < NPB) ncnt[tid] = 0;
    __syncthreads();
    int base = b * SLACK, end = cur[b];
    for (int j = base + tid; j < end; j += 256)
        atomicAdd(&ncnt[(part[j] >> 17) & 127], 1);
    __syncthreads();
    if (tid < NPB) {
        int v = b * NPB + tid;
        if (v < N_NODES) dinv[v] = rsqrtf((float)(ncnt[tid] + 1));  // +1 self-loop
    }
}

// ---------------- layer kernels (g, h stored fp16: row = 16 halves = 32B) ----------------

__device__ __forceinline__ void pack_store_row(__half* dstp, int v, const float* o) {
    int4 w0, w1;
    __half2 q;
    q = __floats2half2_rn(o[0],  o[1]);  w0.x = *(int*)&q;
    q = __floats2half2_rn(o[2],  o[3]);  w0.y = *(int*)&q;
    q = __floats2half2_rn(o[4],  o[5]);  w0.z = *(int*)&q;
    q = __floats2half2_rn(o[6],  o[7]);  w0.w = *(int*)&q;
    q = __floats2half2_rn(o[8],  o[9]);  w1.x = *(int*)&q;
    q = __floats2half2_rn(o[10], o[11]); w1.y = *(int*)&q;
    q = __floats2half2_rn(o[12], o[13]); w1.z = *(int*)&q;
    q = __floats2half2_rn(o[14], o[15]); w1.w = *(int*)&q;
    ((int4*)dstp)[v * 2]     = w0;
    ((int4*)dstp)[v * 2 + 1] = w1;
}

// g[v] = dinv[v] * (x[v] @ W1), x: [N,128] fp32, W: [128,16], g: fp16
__global__ void transform_x_kernel(const float* __restrict__ x, const float* __restrict__ W,
                                   const float* __restrict__ dinv, __half* __restrict__ g) {
    __shared__ float Wl[N_FEAT * HIDDEN];
    int tid = threadIdx.x;
    for (int i = tid; i < N_FEAT * HIDDEN; i += 256) Wl[i] = W[i];
    __syncthreads();
    int v = blockIdx.x * 256 + tid;
    if (v >= N_NODES) return;
    float acc[HIDDEN];
#pragma unroll
    for (int f = 0; f < HIDDEN; ++f) acc[f] = 0.f;
    const float4* xr = (const float4*)(x + (size_t)v * N_FEAT);
#pragma unroll 4
    for (int k4 = 0; k4 < N_FEAT / 4; ++k4) {
        float4 xv = xr[k4];
        const float* wr = &Wl[k4 * 4 * HIDDEN];
#pragma unroll
        for (int f = 0; f < HIDDEN; ++f)
            acc[f] += xv.x * wr[f] + xv.y * wr[HIDDEN + f] +
                      xv.z * wr[2 * HIDDEN + f] + xv.w * wr[3 * HIDDEN + f];
    }
    float di = dinv[v];
#pragma unroll
    for (int f = 0; f < HIDDEN; ++f) acc[f] *= di;
    pack_store_row(g, v, acc);
}

// g[v] = dinv[v] * (h[v] @ W), h: [N,16] fp16, W: [16,16], g: fp16
__global__ void transform_h_kernel(const __half* __restrict__ h, const float* __restrict__ W,
                                   const float* __restrict__ dinv, __half* __restrict__ g) {
    __shared__ float Wl[HIDDEN * HIDDEN];
    int tid = threadIdx.x;
    if (tid < HIDDEN * HIDDEN) Wl[tid] = W[tid];
    __syncthreads();
    int v = blockIdx.x * 256 + tid;
    if (v >= N_NODES) return;
    int4 r0 = ((const int4*)h)[v * 2];
    int4 r1 = ((const int4*)h)[v * 2 + 1];
    float hv[HIDDEN];
    {
        const int rr[8] = {r0.x, r0.y, r0.z, r0.w, r1.x, r1.y, r1.z, r1.w};
#pragma unroll
        for (int q = 0; q < 8; ++q) {
            __half2 p = *(const __half2*)&rr[q];
            float2 f2 = __half22float2(p);
            hv[q * 2] = f2.x; hv[q * 2 + 1] = f2.y;
        }
    }
    float acc[HIDDEN];
#pragma unroll
    for (int f = 0; f < HIDDEN; ++f) acc[f] = 0.f;
#pragma unroll
    for (int k = 0; k < HIDDEN; ++k) {
        float hk = hv[k];
#pragma unroll
        for (int f = 0; f < HIDDEN; ++f) acc[f] += hk * Wl[k * HIDDEN + f];
    }
    float di = dinv[v];
#pragma unroll
    for (int f = 0; f < HIDDEN; ++f) acc[f] *= di;
    pack_store_row(g, v, acc);
}

// ---------------- aggregate v2: LDS accumulators per bucket, no CSR ----------------
// block b owns dst nodes [b*128, b*128+128); 2 lanes per edge (hh = feature half)
// acc stride 17 (17 coprime 32) spreads banks for the fp32 LDS atomics

__global__ void aggregate_kernel(const __half* __restrict__ g, const unsigned* __restrict__ part,
                                 const int* __restrict__ cur, const float* __restrict__ dinv,
                                 const float* __restrict__ bias, __half* __restrict__ hout,
                                 int do_relu) {
    __shared__ float acc[NPB * 17];
    int b   = blockIdx.x;
    int tid = threadIdx.x;
    for (int i = tid; i < NPB * 17; i += 256) acc[i] = 0.f;
    __syncthreads();
    int base = b * SLACK, end = cur[b];
    int p  = tid >> 1;
    int hh = tid & 1;
    const int4* g4 = (const int4*)g;
    for (int j = base + p; j < end; j += 128) {
        unsigned r = part[j];
        int s = r & 0x1FFFF;
        int d = (r >> 17) & 127;
        int4 rv = g4[s * 2 + hh];
        float2 f0 = __half22float2(*(const __half2*)&rv.x);
        float2 f1 = __half22float2(*(const __half2*)&rv.y);
        float2 f2 = __half22float2(*(const __half2*)&rv.z);
        float2 f3 = __half22float2(*(const __half2*)&rv.w);
        float* a = &acc[d * 17 + hh * 8];
        __hip_atomic_fetch_add(&a[0], f0.x, __ATOMIC_RELAXED, __HIP_MEMORY_SCOPE_WORKGROUP);
        __hip_atomic_fetch_add(&a[1], f0.y, __ATOMIC_RELAXED, __HIP_MEMORY_SCOPE_WORKGROUP);
        __hip_atomic_fetch_add(&a[2], f1.x, __ATOMIC_RELAXED, __HIP_MEMORY_SCOPE_WORKGROUP);
        __hip_atomic_fetch_add(&a[3], f1.y, __ATOMIC_RELAXED, __HIP_MEMORY_SCOPE_WORKGROUP);
        __hip_atomic_fetch_add(&a[4], f2.x, __ATOMIC_RELAXED, __HIP_MEMORY_SCOPE_WORKGROUP);
        __hip_atomic_fetch_add(&a[5], f2.y, __ATOMIC_RELAXED, __HIP_MEMORY_SCOPE_WORKGROUP);
        __hip_atomic_fetch_add(&a[6], f3.x, __ATOMIC_RELAXED, __HIP_MEMORY_SCOPE_WORKGROUP);
        __hip_atomic_fetch_add(&a[7], f3.y, __ATOMIC_RELAXED, __HIP_MEMORY_SCOPE_WORKGROUP);
    }
    __syncthreads();
    if (tid < NPB) {
        int v = b * NPB + tid;
        if (v < N_NODES) {
            int4 r0 = g4[v * 2];       // self-loop contribution
            int4 r1 = g4[v * 2 + 1];
            float self[16];
            {
                const int rr[8] = {r0.x, r0.y, r0.z, r0.w, r1.x, r1.y, r1.z, r1.w};
#pragma unroll
                for (int q = 0; q < 8; ++q) {
                    float2 f2 = __half22float2(*(const __half2*)&rr[q]);
                    self[q * 2] = f2.x; self[q * 2 + 1] = f2.y;
                }
            }
            float di = dinv[v];
            float o[16];
#pragma unroll
            for (int f = 0; f < HIDDEN; ++f) {
                float val = di * (acc[tid * 17 + f] + self[f]) + bias[f];
                o[f] = do_relu ? fmaxf(val, 0.f) : val;
            }
            pack_store_row(hout, v, o);
        }
    }
}

// ---------------- fused pooling + head (batch is sorted -> contiguous graph ranges) ----------------

__global__ void pool_head_kernel(const __half* __restrict__ h, const int* __restrict__ batch,
                                 const float* __restrict__ Wlin, const float* __restrict__ blin,
                                 float* __restrict__ out) {
    __shared__ float red[256];
    __shared__ int bounds[2];
    int g   = blockIdx.x;
    int tid = threadIdx.x;
    if (tid < 2) {
        int target = g + tid;   // lower_bound(batch, target)
        int lo = 0, hi = N_NODES;
        while (lo < hi) {
            int mid = (lo + hi) >> 1;
            if (batch[mid] < target) lo = mid + 1; else hi = mid;
        }
        bounds[tid] = lo;
    }
    __syncthreads();
    int start = bounds[0], end = bounds[1];
    int f = tid & 15, r = tid >> 4;
    float acc = 0.f;
    for (int v = start + r; v < end; v += 16)
        acc += __half2float(h[v * HIDDEN + f]);
    red[tid] = acc;
    __syncthreads();
    for (int off = 128; off >= 16; off >>= 1) {
        if (tid < off) red[tid] += red[tid + off];
        __syncthreads();
    }
    if (tid < N_CLASSES) {
        float s = blin[tid];
#pragma unroll
        for (int fe = 0; fe < HIDDEN; ++fe) s += red[fe] * Wlin[fe * N_CLASSES + tid];
        out[g * N_CLASSES + tid] = s;
    }
}

// ---------------- launch ----------------

extern "C" void kernel_launch(void* const* d_in, const int* in_sizes, int n_in,
                              void* d_out, int out_size, void* d_ws, size_t ws_size,
                              hipStream_t stream) {
    const float* x     = (const float*)d_in[0];
    const int*   ei    = (const int*)d_in[1];
    const int*   src   = ei;
    const int*   dst   = ei + N_EDGES;
    const int*   batch = (const int*)d_in[2];
    const float* W1 = (const float*)d_in[3];
    const float* b1 = (const float*)d_in[4];
    const float* W2 = (const float*)d_in[5];
    const float* b2 = (const float*)d_in[6];
    const float* W3 = (const float*)d_in[7];
    const float* b3 = (const float*)d_in[8];
    const float* Wlin = (const float*)d_in[9];
    const float* blin = (const float*)d_in[10];
    float* out = (float*)d_out;

    char* w = (char*)d_ws;
    auto alloc = [&](size_t bytes) -> char* {
        char* p = w;
        w += (bytes + 255) & ~(size_t)255;
        return p;
    };
    int*    cur   = (int*)alloc((size_t)NBUCKET * 4);
    float*  dinv  = (float*)alloc((size_t)N_NODES * 4);
    __half* g     = (__half*)alloc((size_t)N_NODES * HIDDEN * 2);
    __half* hA    = (__half*)alloc((size_t)N_NODES * HIDDEN * 2);
    __half* hB    = (__half*)alloc((size_t)N_NODES * HIDDEN * 2);
    unsigned* part = (unsigned*)alloc((size_t)NBUCKET * SLACK * 4);  // 14.4 MB

    int nbn = (N_NODES + 255) / 256;
    int pb  = (N_EDGES + 256 * EPT - 1) / (256 * EPT);

    cursor_init_kernel<<<(NBUCKET + 255) / 256, 256, 0, stream>>>(cur);
    partition_kernel<<<pb, 256, 0, stream>>>(src, dst, cur, part);
    deg_dinv_kernel<<<NBUCKET, 256, 0, stream>>>(part, cur, dinv);

    // layer 1
    transform_x_kernel<<<nbn, 256, 0, stream>>>(x, W1, dinv, g);
    aggregate_kernel<<<NBUCKET, 256, 0, stream>>>(g, part, cur, dinv, b1, hA, 1);
    // layer 2
    transform_h_kernel<<<nbn, 256, 0, stream>>>(hA, W2, dinv, g);
    aggregate_kernel<<<NBUCKET, 256, 0, stream>>>(g, part, cur, dinv, b2, hB, 1);
    // layer 3 (no relu)
    transform_h_kernel<<<nbn, 256, 0, stream>>>(hB, W3, dinv, g);
    aggregate_kernel<<<NBUCKET, 256, 0, stream>>>(g, part, cur, dinv, b3, hA, 0);

    pool_head_kernel<<<N_GRAPHS, 256, 0, stream>>>(hA, batch, Wlin, blin, out);
}

// Round 6
// 290.207 us; speedup vs baseline: 4.1472x; 4.1472x over previous
//
#include <hip/hip_runtime.h>
#include <hip/hip_fp16.h>

#define N_NODES   100000
#define N_EDGES   3200000
#define N_FEAT    128
#define HIDDEN    16
#define N_CLASSES 10
#define N_GRAPHS  512
#define NPB       256                      // nodes per bucket
#define NBUCKET   391                      // ceil(N_NODES / NPB)
#define SLACK     9216                     // mean 8184, sigma ~90 -> +11 sigma
#define EPT       16                       // edges per thread in partition

// ---------------- bucket partition with slack regions (no count/scan prepass) ----------------

__global__ void cursor_init_kernel(int* __restrict__ cur) {
    int i = blockIdx.x * 256 + threadIdx.x;
    if (i < NBUCKET) cur[i] = i * SLACK;
}

// two-pass, array-free (no scratch spills): histogram -> reserve -> rank & scatter
// record: src | (dst&255)<<17
__global__ void partition_kernel(const int* __restrict__ src, const int* __restrict__ dst,
                                 int* __restrict__ cur, unsigned* __restrict__ part) {
    __shared__ int cnt[NBUCKET];
    __shared__ int rk[NBUCKET];
    __shared__ int base[NBUCKET];
    int tid = threadIdx.x;
    for (int i = tid; i < NBUCKET; i += 256) { cnt[i] = 0; rk[i] = 0; }
    __syncthreads();
    int s0 = blockIdx.x * (256 * EPT);
#pragma unroll
    for (int i = 0; i < EPT; ++i) {
        int e = s0 + i * 256 + tid;
        if (e < N_EDGES) atomicAdd(&cnt[dst[e] >> 8], 1);
    }
    __syncthreads();
    for (int i = tid; i < NBUCKET; i += 256) {
        int c = cnt[i];
        base[i] = c ? atomicAdd(&cur[i], c) : 0;
    }
    __syncthreads();
#pragma unroll
    for (int i = 0; i < EPT; ++i) {
        int e = s0 + i * 256 + tid;
        if (e < N_EDGES) {
            int d = dst[e];
            int b = d >> 8;
            int r = atomicAdd(&rk[b], 1);
            part[base[b] + r] = (unsigned)src[e] | ((unsigned)(d & 255) << 17);
        }
    }
}

// one block per bucket: count/scan/fill in LDS over the bucket's slack region
__global__ void build_csr_kernel(const unsigned* __restrict__ part, const int* __restrict__ cur,
                                 int* __restrict__ rp_beg, int* __restrict__ rp_end,
                                 float* __restrict__ dinv, int* __restrict__ csr) {
    __shared__ int ncnt[256];
    __shared__ int s[256];
    int b   = blockIdx.x;
    int tid = threadIdx.x;
    int beg = b * SLACK, end = cur[b];
    ncnt[tid] = 0;
    __syncthreads();
    for (int j = beg + tid; j < end; j += 256)
        atomicAdd(&ncnt[(part[j] >> 17) & 255], 1);
    __syncthreads();
    int deg = ncnt[tid];
    s[tid] = deg;
    __syncthreads();
    for (int off = 1; off < 256; off <<= 1) {
        int t = (tid >= off) ? s[tid - off] : 0;
        __syncthreads();
        s[tid] += t;
        __syncthreads();
    }
    int excl = s[tid] - deg;
    int node = b * 256 + tid;
    if (node < N_NODES) {
        rp_beg[node] = beg + excl;
        rp_end[node] = beg + excl + deg;
        dinv[node]   = rsqrtf((float)(deg + 1));  // +1 self-loop
    }
    ncnt[tid] = beg + excl;   // absolute fill cursor
    __syncthreads();
    for (int j = beg + tid; j < end; j += 256) {
        unsigned r = part[j];
        int v = (r >> 17) & 255;
        int slot = atomicAdd(&ncnt[v], 1);
        csr[slot] = (int)(r & 0x1FFFFu);
    }
}

// ---------------- layer kernels (g, h stored fp16: row = 16 halves = 32B) ----------------

__device__ __forceinline__ void pack_store_row(__half* dstp, int v, const float* o) {
    int4 w0, w1;
    __half2 q;
    q = __floats2half2_rn(o[0],  o[1]);  w0.x = *(int*)&q;
    q = __floats2half2_rn(o[2],  o[3]);  w0.y = *(int*)&q;
    q = __floats2half2_rn(o[4],  o[5]);  w0.z = *(int*)&q;
    q = __floats2half2_rn(o[6],  o[7]);  w0.w = *(int*)&q;
    q = __floats2half2_rn(o[8],  o[9]);  w1.x = *(int*)&q;
    q = __floats2half2_rn(o[10], o[11]); w1.y = *(int*)&q;
    q = __floats2half2_rn(o[12], o[13]); w1.z = *(int*)&q;
    q = __floats2half2_rn(o[14], o[15]); w1.w = *(int*)&q;
    ((int4*)dstp)[v * 2]     = w0;
    ((int4*)dstp)[v * 2 + 1] = w1;
}

// g[v] = dinv[v] * (x[v] @ W1), x: [N,128] fp32, W: [128,16], g: fp16
__global__ void transform_x_kernel(const float* __restrict__ x, const float* __restrict__ W,
                                   const float* __restrict__ dinv, __half* __restrict__ g) {
    __shared__ float Wl[N_FEAT * HIDDEN];
    int tid = threadIdx.x;
    for (int i = tid; i < N_FEAT * HIDDEN; i += 256) Wl[i] = W[i];
    __syncthreads();
    int v = blockIdx.x * 256 + tid;
    if (v >= N_NODES) return;
    float acc[HIDDEN];
#pragma unroll
    for (int f = 0; f < HIDDEN; ++f) acc[f] = 0.f;
    const float4* xr = (const float4*)(x + (size_t)v * N_FEAT);
#pragma unroll 4
    for (int k4 = 0; k4 < N_FEAT / 4; ++k4) {
        float4 xv = xr[k4];
        const float* wr = &Wl[k4 * 4 * HIDDEN];
#pragma unroll
        for (int f = 0; f < HIDDEN; ++f)
            acc[f] += xv.x * wr[f] + xv.y * wr[HIDDEN + f] +
                      xv.z * wr[2 * HIDDEN + f] + xv.w * wr[3 * HIDDEN + f];
    }
    float di = dinv[v];
#pragma unroll
    for (int f = 0; f < HIDDEN; ++f) acc[f] *= di;
    pack_store_row(g, v, acc);
}

// g[v] = dinv[v] * (h[v] @ W), h: [N,16] fp16, W: [16,16], g: fp16
__global__ void transform_h_kernel(const __half* __restrict__ h, const float* __restrict__ W,
                                   const float* __restrict__ dinv, __half* __restrict__ g) {
    __shared__ float Wl[HIDDEN * HIDDEN];
    int tid = threadIdx.x;
    if (tid < HIDDEN * HIDDEN) Wl[tid] = W[tid];
    __syncthreads();
    int v = blockIdx.x * 256 + tid;
    if (v >= N_NODES) return;
    int4 r0 = ((const int4*)h)[v * 2];
    int4 r1 = ((const int4*)h)[v * 2 + 1];
    float hv[HIDDEN];
    {
        const int rr[8] = {r0.x, r0.y, r0.z, r0.w, r1.x, r1.y, r1.z, r1.w};
#pragma unroll
        for (int q = 0; q < 8; ++q) {
            __half2 p = *(const __half2*)&rr[q];
            float2 f2 = __half22float2(p);
            hv[q * 2] = f2.x; hv[q * 2 + 1] = f2.y;
        }
    }
    float acc[HIDDEN];
#pragma unroll
    for (int f = 0; f < HIDDEN; ++f) acc[f] = 0.f;
#pragma unroll
    for (int k = 0; k < HIDDEN; ++k) {
        float hk = hv[k];
#pragma unroll
        for (int f = 0; f < HIDDEN; ++f) acc[f] += hk * Wl[k * HIDDEN + f];
    }
    float di = dinv[v];
#pragma unroll
    for (int f = 0; f < HIDDEN; ++f) acc[f] *= di;
    pack_store_row(g, v, acc);
}

// h[v][f] = act( dinv[v] * (g[v][f] + sum_{in-edges} g[src][f]) + bias[f] )
// lane layout in wave: lane = c*16 + vl*2 + hh   (c: edge chunk 0..3, vl: node 0..7, hh: feat half)
__global__ void aggregate_kernel(const __half* __restrict__ g, const int* __restrict__ rp_beg,
                                 const int* __restrict__ rp_end, const int* __restrict__ csr,
                                 const float* __restrict__ dinv, const float* __restrict__ bias,
                                 __half* __restrict__ hout, int do_relu) {
    int tid  = threadIdx.x;
    int wave = tid >> 6;
    int l    = tid & 63;
    int c  = l >> 4;
    int vl = (l & 15) >> 1;
    int hh = l & 1;
    int v = blockIdx.x * 32 + wave * 8 + vl;
    if (v >= N_NODES) return;
    int beg = rp_beg[v];
    int deg = rp_end[v] - beg;
    int j0 = beg + ((deg * c) >> 2);
    int j1 = beg + ((deg * (c + 1)) >> 2);
    const int4* g4 = (const int4*)g;
    float a0 = 0.f, a1 = 0.f, a2 = 0.f, a3 = 0.f, a4 = 0.f, a5 = 0.f, a6 = 0.f, a7 = 0.f;
#pragma unroll 4
    for (int j = j0; j < j1; ++j) {
        int s = csr[j];
        int4 r = g4[s * 2 + hh];
        float2 f0 = __half22float2(*(const __half2*)&r.x);
        float2 f1 = __half22float2(*(const __half2*)&r.y);
        float2 f2 = __half22float2(*(const __half2*)&r.z);
        float2 f3 = __half22float2(*(const __half2*)&r.w);
        a0 += f0.x; a1 += f0.y; a2 += f1.x; a3 += f1.y;
        a4 += f2.x; a5 += f2.y; a6 += f3.x; a7 += f3.y;
    }
    a0 += __shfl_xor(a0, 16); a1 += __shfl_xor(a1, 16);
    a2 += __shfl_xor(a2, 16); a3 += __shfl_xor(a3, 16);
    a4 += __shfl_xor(a4, 16); a5 += __shfl_xor(a5, 16);
    a6 += __shfl_xor(a6, 16); a7 += __shfl_xor(a7, 16);
    a0 += __shfl_xor(a0, 32); a1 += __shfl_xor(a1, 32);
    a2 += __shfl_xor(a2, 32); a3 += __shfl_xor(a3, 32);
    a4 += __shfl_xor(a4, 32); a5 += __shfl_xor(a5, 32);
    a6 += __shfl_xor(a6, 32); a7 += __shfl_xor(a7, 32);
    if (c == 0) {
        int4 r = g4[v * 2 + hh];  // self-loop contribution
        float2 s0 = __half22float2(*(const __half2*)&r.x);
        float2 s1 = __half22float2(*(const __half2*)&r.y);
        float2 s2 = __half22float2(*(const __half2*)&r.z);
        float2 s3 = __half22float2(*(const __half2*)&r.w);
        float di = dinv[v];
        const float4* bp = (const float4*)bias;
        float4 bA = bp[hh * 2];
        float4 bB = bp[hh * 2 + 1];
        float o0 = di * (a0 + s0.x) + bA.x;
        float o1 = di * (a1 + s0.y) + bA.y;
        float o2 = di * (a2 + s1.x) + bA.z;
        float o3 = di * (a3 + s1.y) + bA.w;
        float o4 = di * (a4 + s2.x) + bB.x;
        float o5 = di * (a5 + s2.y) + bB.y;
        float o6 = di * (a6 + s3.x) + bB.z;
        float o7 = di * (a7 + s3.y) + bB.w;
        if (do_relu) {
            o0 = fmaxf(o0, 0.f); o1 = fmaxf(o1, 0.f); o2 = fmaxf(o2, 0.f); o3 = fmaxf(o3, 0.f);
            o4 = fmaxf(o4, 0.f); o5 = fmaxf(o5, 0.f); o6 = fmaxf(o6, 0.f); o7 = fmaxf(o7, 0.f);
        }
        int4 w;
        __half2 q;
        q = __floats2half2_rn(o0, o1); w.x = *(int*)&q;
        q = __floats2half2_rn(o2, o3); w.y = *(int*)&q;
        q = __floats2half2_rn(o4, o5); w.z = *(int*)&q;
        q = __floats2half2_rn(o6, o7); w.w = *(int*)&q;
        ((int4*)hout)[v * 2 + hh] = w;
    }
}

// ---------------- fused pooling + head (batch is sorted -> contiguous graph ranges) ----------------

__global__ void pool_head_kernel(const __half* __restrict__ h, const int* __restrict__ batch,
                                 const float* __restrict__ Wlin, const float* __restrict__ blin,
                                 float* __restrict__ out) {
    __shared__ float red[256];
    __shared__ int bounds[2];
    int g   = blockIdx.x;
    int tid = threadIdx.x;
    if (tid < 2) {
        int target = g + tid;   // lower_bound(batch, target)
        int lo = 0, hi = N_NODES;
        while (lo < hi) {
            int mid = (lo + hi) >> 1;
            if (batch[mid] < target) lo = mid + 1; else hi = mid;
        }
        bounds[tid] = lo;
    }
    __syncthreads();
    int start = bounds[0], end = bounds[1];
    int f = tid & 15, r = tid >> 4;
    float acc = 0.f;
    for (int v = start + r; v < end; v += 16)
        acc += __half2float(h[v * HIDDEN + f]);
    red[tid] = acc;
    __syncthreads();
    for (int off = 128; off >= 16; off >>= 1) {
        if (tid < off) red[tid] += red[tid + off];
        __syncthreads();
    }
    if (tid < N_CLASSES) {
        float s = blin[tid];
#pragma unroll
        for (int fe = 0; fe < HIDDEN; ++fe) s += red[fe] * Wlin[fe * N_CLASSES + tid];
        out[g * N_CLASSES + tid] = s;
    }
}

// ---------------- launch ----------------

extern "C" void kernel_launch(void* const* d_in, const int* in_sizes, int n_in,
                              void* d_out, int out_size, void* d_ws, size_t ws_size,
                              hipStream_t stream) {
    const float* x     = (const float*)d_in[0];
    const int*   ei    = (const int*)d_in[1];
    const int*   src   = ei;
    const int*   dst   = ei + N_EDGES;
    const int*   batch = (const int*)d_in[2];
    const float* W1 = (const float*)d_in[3];
    const float* b1 = (const float*)d_in[4];
    const float* W2 = (const float*)d_in[5];
    const float* b2 = (const float*)d_in[6];
    const float* W3 = (const float*)d_in[7];
    const float* b3 = (const float*)d_in[8];
    const float* Wlin = (const float*)d_in[9];
    const float* blin = (const float*)d_in[10];
    float* out = (float*)d_out;

    char* w = (char*)d_ws;
    auto alloc = [&](size_t bytes) -> char* {
        char* p = w;
        w += (bytes + 255) & ~(size_t)255;
        return p;
    };
    int*    cur    = (int*)alloc((size_t)NBUCKET * 4);
    int*    rp_beg = (int*)alloc((size_t)N_NODES * 4);
    int*    rp_end = (int*)alloc((size_t)N_NODES * 4);
    float*  dinv   = (float*)alloc((size_t)N_NODES * 4);
    __half* g      = (__half*)alloc((size_t)N_NODES * HIDDEN * 2);
    __half* hA     = (__half*)alloc((size_t)N_NODES * HIDDEN * 2);
    __half* hB     = (__half*)alloc((size_t)N_NODES * HIDDEN * 2);
    unsigned* part = (unsigned*)alloc((size_t)NBUCKET * SLACK * 4);  // 14.4 MB
    int*    csr    = (int*)alloc((size_t)NBUCKET * SLACK * 4);       // 14.4 MB

    int nbn = (N_NODES + 255) / 256;
    int ab  = (N_NODES + 31) / 32;
    int pb  = (N_EDGES + 256 * EPT - 1) / (256 * EPT);

    cursor_init_kernel<<<(NBUCKET + 255) / 256, 256, 0, stream>>>(cur);
    partition_kernel<<<pb, 256, 0, stream>>>(src, dst, cur, part);
    build_csr_kernel<<<NBUCKET, 256, 0, stream>>>(part, cur, rp_beg, rp_end, dinv, csr);

    // layer 1
    transform_x_kernel<<<nbn, 256, 0, stream>>>(x, W1, dinv, g);
    aggregate_kernel<<<ab, 256, 0, stream>>>(g, rp_beg, rp_end, csr, dinv, b1, hA, 1);
    // layer 2
    transform_h_kernel<<<nbn, 256, 0, stream>>>(hA, W2, dinv, g);
    aggregate_kernel<<<ab, 256, 0, stream>>>(g, rp_beg, rp_end, csr, dinv, b2, hB, 1);
    // layer 3 (no relu)
    transform_h_kernel<<<nbn, 256, 0, stream>>>(hB, W3, dinv, g);
    aggregate_kernel<<<ab, 256, 0, stream>>>(g, rp_beg, rp_end, csr, dinv, b3, hA, 0);

    pool_head_kernel<<<N_GRAPHS, 256, 0, stream>>>(hA, batch, Wlin, blin, out);
}

// Round 7
// 289.165 us; speedup vs baseline: 4.1621x; 1.0036x over previous
//
#include <hip/hip_runtime.h>
#include <hip/hip_fp16.h>

#define N_NODES   100000
#define N_EDGES   3200000
#define N_FEAT    128
#define HIDDEN    16
#define N_CLASSES 10
#define N_GRAPHS  512
#define NPB       256                      // dst nodes per bucket
#define NBUCKET   391                      // ceil(N_NODES / NPB)
#define EPB       8192                     // edges per partition block
#define PBLK      ((N_EDGES + EPB - 1) / EPB)   // 391
#define PSLACK    12288                    // part stride/bucket: mean 8184 + pad ~2933 + 9 sigma
#define CSLACK    9216                     // csr stride/bucket: mean 8184 + 11 sigma

// ---------------- partition: LDS counting sort + line-aligned flush ----------------

__global__ void cursor_init_kernel(int* __restrict__ cur) {
    int i = blockIdx.x * 256 + threadIdx.x;
    if (i < NBUCKET) cur[i] = i * PSLACK;
}

// record: src | (dst&255)<<17 ; sentinel 0xFFFFFFFF fills the 64B-alignment padding
__global__ __launch_bounds__(512) void partition_kernel(const int* __restrict__ src,
                                                        const int* __restrict__ dst,
                                                        int* __restrict__ cur,
                                                        unsigned* __restrict__ part) {
    __shared__ int cnt[NBUCKET];
    __shared__ int lbase[NBUCKET];
    __shared__ int rk[NBUCKET];
    __shared__ int gbase[NBUCKET];
    __shared__ int s[512];
    __shared__ unsigned sorted[EPB];
    int tid = threadIdx.x;
    for (int i = tid; i < NBUCKET; i += 512) cnt[i] = 0;
    __syncthreads();
    int s0 = blockIdx.x * EPB;
    // pass 1: histogram
#pragma unroll
    for (int i = 0; i < EPB / 512; ++i) {
        int e = s0 + i * 512 + tid;
        if (e < N_EDGES) atomicAdd(&cnt[dst[e] >> 8], 1);
    }
    __syncthreads();
    // block-local exclusive scan -> lbase
    int v = (tid < NBUCKET) ? cnt[tid] : 0;
    s[tid] = v;
    __syncthreads();
    for (int off = 1; off < 512; off <<= 1) {
        int t = (tid >= off) ? s[tid - off] : 0;
        __syncthreads();
        s[tid] += t;
        __syncthreads();
    }
    if (tid < NBUCKET) {
        int lb = s[tid] - v;
        lbase[tid] = lb;
        rk[tid]    = lb;
        int cpad = (v + 15) & ~15;                 // 64B-aligned reservation
        gbase[tid] = cpad ? atomicAdd(&cur[tid], cpad) : 0;
    }
    __syncthreads();
    // pass 2: re-read edges (L2-hot), rank-scatter into LDS
#pragma unroll
    for (int i = 0; i < EPB / 512; ++i) {
        int e = s0 + i * 512 + tid;
        if (e < N_EDGES) {
            int d = dst[e];
            int b = d >> 8;
            int r = atomicAdd(&rk[b], 1);
            sorted[r] = (unsigned)src[e] | ((unsigned)(d & 255) << 17);
        }
    }
    __syncthreads();
    // flush: one wave per bucket; contiguous, 64B-aligned, fully-written lines
    int wave = tid >> 6, lane = tid & 63;
    for (int b = wave; b < NBUCKET; b += 8) {
        int c = cnt[b];
        if (!c) continue;
        int cpad = (c + 15) & ~15;
        int lb = lbase[b], gb = gbase[b];
        for (int j = lane; j < cpad; j += 64)
            part[gb + j] = (j < c) ? sorted[lb + j] : 0xFFFFFFFFu;
    }
}

// one block per bucket: count/scan/fill in LDS over the bucket's slack region (skip sentinels)
__global__ void build_csr_kernel(const unsigned* __restrict__ part, const int* __restrict__ cur,
                                 int* __restrict__ rp_beg, int* __restrict__ rp_end,
                                 float* __restrict__ dinv, int* __restrict__ csr) {
    __shared__ int ncnt[256];
    __shared__ int s[256];
    int b   = blockIdx.x;
    int tid = threadIdx.x;
    int beg = b * PSLACK, end = cur[b];
    ncnt[tid] = 0;
    __syncthreads();
    for (int j = beg + tid; j < end; j += 256) {
        unsigned r = part[j];
        if (r != 0xFFFFFFFFu) atomicAdd(&ncnt[(r >> 17) & 255], 1);
    }
    __syncthreads();
    int deg = ncnt[tid];
    s[tid] = deg;
    __syncthreads();
    for (int off = 1; off < 256; off <<= 1) {
        int t = (tid >= off) ? s[tid - off] : 0;
        __syncthreads();
        s[tid] += t;
        __syncthreads();
    }
    int excl = s[tid] - deg;
    int node = b * 256 + tid;
    int cbeg = b * CSLACK;
    if (node < N_NODES) {
        rp_beg[node] = cbeg + excl;
        rp_end[node] = cbeg + excl + deg;
        dinv[node]   = rsqrtf((float)(deg + 1));  // +1 self-loop
    }
    ncnt[tid] = cbeg + excl;   // absolute fill cursor
    __syncthreads();
    for (int j = beg + tid; j < end; j += 256) {
        unsigned r = part[j];
        if (r != 0xFFFFFFFFu) {
            int v = (r >> 17) & 255;
            int slot = atomicAdd(&ncnt[v], 1);
            csr[slot] = (int)(r & 0x1FFFFu);
        }
    }
}

// ---------------- layer kernels (g, h stored fp16: row = 16 halves = 32B) ----------------

__device__ __forceinline__ void pack_store_row(__half* dstp, int v, const float* o) {
    int4 w0, w1;
    __half2 q;
    q = __floats2half2_rn(o[0],  o[1]);  w0.x = *(int*)&q;
    q = __floats2half2_rn(o[2],  o[3]);  w0.y = *(int*)&q;
    q = __floats2half2_rn(o[4],  o[5]);  w0.z = *(int*)&q;
    q = __floats2half2_rn(o[6],  o[7]);  w0.w = *(int*)&q;
    q = __floats2half2_rn(o[8],  o[9]);  w1.x = *(int*)&q;
    q = __floats2half2_rn(o[10], o[11]); w1.y = *(int*)&q;
    q = __floats2half2_rn(o[12], o[13]); w1.z = *(int*)&q;
    q = __floats2half2_rn(o[14], o[15]); w1.w = *(int*)&q;
    ((int4*)dstp)[v * 2]     = w0;
    ((int4*)dstp)[v * 2 + 1] = w1;
}

// g[v] = dinv[v] * (x[v] @ W1), x: [N,128] fp32, W: [128,16], g: fp16
__global__ void transform_x_kernel(const float* __restrict__ x, const float* __restrict__ W,
                                   const float* __restrict__ dinv, __half* __restrict__ g) {
    __shared__ float Wl[N_FEAT * HIDDEN];
    int tid = threadIdx.x;
    for (int i = tid; i < N_FEAT * HIDDEN; i += 256) Wl[i] = W[i];
    __syncthreads();
    int v = blockIdx.x * 256 + tid;
    if (v >= N_NODES) return;
    float acc[HIDDEN];
#pragma unroll
    for (int f = 0; f < HIDDEN; ++f) acc[f] = 0.f;
    const float4* xr = (const float4*)(x + (size_t)v * N_FEAT);
#pragma unroll 4
    for (int k4 = 0; k4 < N_FEAT / 4; ++k4) {
        float4 xv = xr[k4];
        const float* wr = &Wl[k4 * 4 * HIDDEN];
#pragma unroll
        for (int f = 0; f < HIDDEN; ++f)
            acc[f] += xv.x * wr[f] + xv.y * wr[HIDDEN + f] +
                      xv.z * wr[2 * HIDDEN + f] + xv.w * wr[3 * HIDDEN + f];
    }
    float di = dinv[v];
#pragma unroll
    for (int f = 0; f < HIDDEN; ++f) acc[f] *= di;
    pack_store_row(g, v, acc);
}

// g[v] = dinv[v] * (h[v] @ W), h: [N,16] fp16, W: [16,16], g: fp16
__global__ void transform_h_kernel(const __half* __restrict__ h, const float* __restrict__ W,
                                   const float* __restrict__ dinv, __half* __restrict__ g) {
    __shared__ float Wl[HIDDEN * HIDDEN];
    int tid = threadIdx.x;
    if (tid < HIDDEN * HIDDEN) Wl[tid] = W[tid];
    __syncthreads();
    int v = blockIdx.x * 256 + tid;
    if (v >= N_NODES) return;
    int4 r0 = ((const int4*)h)[v * 2];
    int4 r1 = ((const int4*)h)[v * 2 + 1];
    float hv[HIDDEN];
    {
        const int rr[8] = {r0.x, r0.y, r0.z, r0.w, r1.x, r1.y, r1.z, r1.w};
#pragma unroll
        for (int q = 0; q < 8; ++q) {
            __half2 p = *(const __half2*)&rr[q];
            float2 f2 = __half22float2(p);
            hv[q * 2] = f2.x; hv[q * 2 + 1] = f2.y;
        }
    }
    float acc[HIDDEN];
#pragma unroll
    for (int f = 0; f < HIDDEN; ++f) acc[f] = 0.f;
#pragma unroll
    for (int k = 0; k < HIDDEN; ++k) {
        float hk = hv[k];
#pragma unroll
        for (int f = 0; f < HIDDEN; ++f) acc[f] += hk * Wl[k * HIDDEN + f];
    }
    float di = dinv[v];
#pragma unroll
    for (int f = 0; f < HIDDEN; ++f) acc[f] *= di;
    pack_store_row(g, v, acc);
}

// h[v][f] = act( dinv[v] * (g[v][f] + sum_{in-edges} g[src][f]) + bias[f] )
// lane layout: lane = c*8 + vl*2 + hh  (c: edge chunk 0..7, vl: node 0..3, hh: feat half)
__global__ void aggregate_kernel(const __half* __restrict__ g, const int* __restrict__ rp_beg,
                                 const int* __restrict__ rp_end, const int* __restrict__ csr,
                                 const float* __restrict__ dinv, const float* __restrict__ bias,
                                 __half* __restrict__ hout, int do_relu) {
    int tid  = threadIdx.x;
    int wave = tid >> 6;
    int l    = tid & 63;
    int c  = l >> 3;
    int vl = (l >> 1) & 3;
    int hh = l & 1;
    int v = blockIdx.x * 16 + wave * 4 + vl;
    if (v >= N_NODES) return;
    int beg = rp_beg[v];
    int deg = rp_end[v] - beg;
    int j0 = beg + ((deg * c) >> 3);
    int j1 = beg + ((deg * (c + 1)) >> 3);
    const int4* g4 = (const int4*)g;
    float a0 = 0.f, a1 = 0.f, a2 = 0.f, a3 = 0.f, a4 = 0.f, a5 = 0.f, a6 = 0.f, a7 = 0.f;
#pragma unroll 4
    for (int j = j0; j < j1; ++j) {
        int s = csr[j];
        int4 r = g4[s * 2 + hh];
        float2 f0 = __half22float2(*(const __half2*)&r.x);
        float2 f1 = __half22float2(*(const __half2*)&r.y);
        float2 f2 = __half22float2(*(const __half2*)&r.z);
        float2 f3 = __half22float2(*(const __half2*)&r.w);
        a0 += f0.x; a1 += f0.y; a2 += f1.x; a3 += f1.y;
        a4 += f2.x; a5 += f2.y; a6 += f3.x; a7 += f3.y;
    }
    // combine the 8 edge-chunk partials (lanes differing in bits 3,4,5)
    a0 += __shfl_xor(a0, 8);  a1 += __shfl_xor(a1, 8);
    a2 += __shfl_xor(a2, 8);  a3 += __shfl_xor(a3, 8);
    a4 += __shfl_xor(a4, 8);  a5 += __shfl_xor(a5, 8);
    a6 += __shfl_xor(a6, 8);  a7 += __shfl_xor(a7, 8);
    a0 += __shfl_xor(a0, 16); a1 += __shfl_xor(a1, 16);
    a2 += __shfl_xor(a2, 16); a3 += __shfl_xor(a3, 16);
    a4 += __shfl_xor(a4, 16); a5 += __shfl_xor(a5, 16);
    a6 += __shfl_xor(a6, 16); a7 += __shfl_xor(a7, 16);
    a0 += __shfl_xor(a0, 32); a1 += __shfl_xor(a1, 32);
    a2 += __shfl_xor(a2, 32); a3 += __shfl_xor(a3, 32);
    a4 += __shfl_xor(a4, 32); a5 += __shfl_xor(a5, 32);
    a6 += __shfl_xor(a6, 32); a7 += __shfl_xor(a7, 32);
    if (c == 0) {
        int4 r = g4[v * 2 + hh];  // self-loop contribution
        float2 s0 = __half22float2(*(const __half2*)&r.x);
        float2 s1 = __half22float2(*(const __half2*)&r.y);
        float2 s2 = __half22float2(*(const __half2*)&r.z);
        float2 s3 = __half22float2(*(const __half2*)&r.w);
        float di = dinv[v];
        const float4* bp = (const float4*)bias;
        float4 bA = bp[hh * 2];
        float4 bB = bp[hh * 2 + 1];
        float o0 = di * (a0 + s0.x) + bA.x;
        float o1 = di * (a1 + s0.y) + bA.y;
        float o2 = di * (a2 + s1.x) + bA.z;
        float o3 = di * (a3 + s1.y) + bA.w;
        float o4 = di * (a4 + s2.x) + bB.x;
        float o5 = di * (a5 + s2.y) + bB.y;
        float o6 = di * (a6 + s3.x) + bB.z;
        float o7 = di * (a7 + s3.y) + bB.w;
        if (do_relu) {
            o0 = fmaxf(o0, 0.f); o1 = fmaxf(o1, 0.f); o2 = fmaxf(o2, 0.f); o3 = fmaxf(o3, 0.f);
            o4 = fmaxf(o4, 0.f); o5 = fmaxf(o5, 0.f); o6 = fmaxf(o6, 0.f); o7 = fmaxf(o7, 0.f);
        }
        int4 w;
        __half2 q;
        q = __floats2half2_rn(o0, o1); w.x = *(int*)&q;
        q = __floats2half2_rn(o2, o3); w.y = *(int*)&q;
        q = __floats2half2_rn(o4, o5); w.z = *(int*)&q;
        q = __floats2half2_rn(o6, o7); w.w = *(int*)&q;
        ((int4*)hout)[v * 2 + hh] = w;
    }
}

// ---------------- fused pooling + head (batch is sorted -> contiguous graph ranges) ----------------

__global__ void pool_head_kernel(const __half* __restrict__ h, const int* __restrict__ batch,
                                 const float* __restrict__ Wlin, const float* __restrict__ blin,
                                 float* __restrict__ out) {
    __shared__ float red[256];
    __shared__ int bounds[2];
    int g   = blockIdx.x;
    int tid = threadIdx.x;
    if (tid < 2) {
        int target = g + tid;   // lower_bound(batch, target)
        int lo = 0, hi = N_NODES;
        while (lo < hi) {
            int mid = (lo + hi) >> 1;
            if (batch[mid] < target) lo = mid + 1; else hi = mid;
        }
        bounds[tid] = lo;
    }
    __syncthreads();
    int start = bounds[0], end = bounds[1];
    int f = tid & 15, r = tid >> 4;
    float acc = 0.f;
    for (int v = start + r; v < end; v += 16)
        acc += __half2float(h[v * HIDDEN + f]);
    red[tid] = acc;
    __syncthreads();
    for (int off = 128; off >= 16; off >>= 1) {
        if (tid < off) red[tid] += red[tid + off];
        __syncthreads();
    }
    if (tid < N_CLASSES) {
        float s = blin[tid];
#pragma unroll
        for (int fe = 0; fe < HIDDEN; ++fe) s += red[fe] * Wlin[fe * N_CLASSES + tid];
        out[g * N_CLASSES + tid] = s;
    }
}

// ---------------- launch ----------------

extern "C" void kernel_launch(void* const* d_in, const int* in_sizes, int n_in,
                              void* d_out, int out_size, void* d_ws, size_t ws_size,
                              hipStream_t stream) {
    const float* x     = (const float*)d_in[0];
    const int*   ei    = (const int*)d_in[1];
    const int*   src   = ei;
    const int*   dst   = ei + N_EDGES;
    const int*   batch = (const int*)d_in[2];
    const float* W1 = (const float*)d_in[3];
    const float* b1 = (const float*)d_in[4];
    const float* W2 = (const float*)d_in[5];
    const float* b2 = (const float*)d_in[6];
    const float* W3 = (const float*)d_in[7];
    const float* b3 = (const float*)d_in[8];
    const float* Wlin = (const float*)d_in[9];
    const float* blin = (const float*)d_in[10];
    float* out = (float*)d_out;

    char* w = (char*)d_ws;
    auto alloc = [&](size_t bytes) -> char* {
        char* p = w;
        w += (bytes + 255) & ~(size_t)255;
        return p;
    };
    int*    cur    = (int*)alloc((size_t)NBUCKET * 4);
    int*    rp_beg = (int*)alloc((size_t)N_NODES * 4);
    int*    rp_end = (int*)alloc((size_t)N_NODES * 4);
    float*  dinv   = (float*)alloc((size_t)N_NODES * 4);
    __half* g      = (__half*)alloc((size_t)N_NODES * HIDDEN * 2);
    __half* hA     = (__half*)alloc((size_t)N_NODES * HIDDEN * 2);
    __half* hB     = (__half*)alloc((size_t)N_NODES * HIDDEN * 2);
    unsigned* part = (unsigned*)alloc((size_t)NBUCKET * PSLACK * 4);  // 19.2 MB
    int*    csr    = (int*)alloc((size_t)NBUCKET * CSLACK * 4);       // 14.4 MB

    int nbn = (N_NODES + 255) / 256;
    int ab  = (N_NODES + 15) / 16;

    cursor_init_kernel<<<(NBUCKET + 255) / 256, 256, 0, stream>>>(cur);
    partition_kernel<<<PBLK, 512, 0, stream>>>(src, dst, cur, part);
    build_csr_kernel<<<NBUCKET, 256, 0, stream>>>(part, cur, rp_beg, rp_end, dinv, csr);

    // layer 1
    transform_x_kernel<<<nbn, 256, 0, stream>>>(x, W1, dinv, g);
    aggregate_kernel<<<ab, 256, 0, stream>>>(g, rp_beg, rp_end, csr, dinv, b1, hA, 1);
    // layer 2
    transform_h_kernel<<<nbn, 256, 0, stream>>>(hA, W2, dinv, g);
    aggregate_kernel<<<ab, 256, 0, stream>>>(g, rp_beg, rp_end, csr, dinv, b2, hB, 1);
    // layer 3 (no relu)
    transform_h_kernel<<<nbn, 256, 0, stream>>>(hB, W3, dinv, g);
    aggregate_kernel<<<ab, 256, 0, stream>>>(g, rp_beg, rp_end, csr, dinv, b3, hA, 0);

    pool_head_kernel<<<N_GRAPHS, 256, 0, stream>>>(hA, batch, Wlin, blin, out);
}